// Round 1
// baseline (961.661 us; speedup 1.0000x reference)
//
#include <hip/hip_runtime.h>

// MCR^2 loss for m x p fp32 x, int labels y in [0,K).
// Fixed by setup_inputs: m=262144, p=128, K=10.
#define K 10
#define P 128
#define EPSV 0.01f
#define GAM1 1.0f
#define GAM2 1.0f
#define CHUNK 512
#define STAGE 64
#define NTHR 256

// ---------------- counting sort: histogram per block ----------------
__global__ void hist_kernel(const int* __restrict__ y, int* __restrict__ blk_counts, int m) {
    __shared__ int h[K];
    int tid = threadIdx.x;
    if (tid < K) h[tid] = 0;
    __syncthreads();
    int base = blockIdx.x * CHUNK;
    int rows = min(CHUNK, m - base);
    for (int i = tid; i < rows; i += NTHR) atomicAdd(&h[y[base + i]], 1);
    __syncthreads();
    if (tid < K) blk_counts[blockIdx.x * K + tid] = h[tid];
}

// ---------------- scan block counts -> absolute offsets, class counts ----
__global__ void scan_kernel(const int* __restrict__ blk_counts, int* __restrict__ blk_offsets,
                            int* __restrict__ counts, int nb) {
    __shared__ int tot[K];
    __shared__ int start[K];
    int tid = threadIdx.x;
    if (tid < K) {
        int run = 0;
        for (int b = 0; b < nb; ++b) {
            blk_offsets[b * K + tid] = run;
            run += blk_counts[b * K + tid];
        }
        tot[tid] = run;
    }
    __syncthreads();
    if (tid == 0) {
        int s = 0;
        for (int c = 0; c < K; ++c) { start[c] = s; s += tot[c]; }
    }
    __syncthreads();
    if (tid < K) {
        counts[tid] = tot[tid];
        int s = start[tid];
        for (int b = 0; b < nb; ++b) blk_offsets[b * K + tid] += s;
    }
}

// ---------------- scatter row indices into class-sorted perm ----------------
__global__ void scatter_kernel(const int* __restrict__ y, const int* __restrict__ blk_offsets,
                               int* __restrict__ perm, int m) {
    __shared__ int cur[K];
    int tid = threadIdx.x;
    if (tid < K) cur[tid] = blk_offsets[blockIdx.x * K + tid];
    __syncthreads();
    int base = blockIdx.x * CHUNK;
    int rows = min(CHUNK, m - base);
    for (int i = tid; i < rows; i += NTHR) {
        int row = base + i;
        int c = y[row];
        int pos = atomicAdd(&cur[c], 1);
        perm[pos] = row;
    }
}

// ---------------- per-class Gram accumulation over sorted rows ----------------
// Block handles CHUNK sorted rows; 256 threads as 16x16 grid, 8x8 fp32 acc each
// (full 128x128 Gram). Flush acc -> global grams[class] via atomicAdd only when
// the class changes (sorted => ~1-2 flushes per block).
__global__ __launch_bounds__(NTHR) void gram_kernel(const float* __restrict__ x,
                                                    const int* __restrict__ y,
                                                    const int* __restrict__ perm,
                                                    float* __restrict__ grams, int m) {
    __shared__ float xs[STAGE * P];         // 32 KB
    __shared__ int cls[CHUNK];
    __shared__ int pm[CHUNK];
    int tid = threadIdx.x;
    int base = blockIdx.x * CHUNK;
    int rows = min(CHUNK, m - base);
    for (int i = tid; i < rows; i += NTHR) {
        int r = perm[base + i];
        pm[i] = r;
        cls[i] = y[r];
    }
    __syncthreads();

    const int ti = tid >> 4;   // 0..15, owns Gram rows ti*8..+8
    const int tj = tid & 15;   // 0..15, owns Gram cols tj*8..+8
    float acc[8][8];
#pragma unroll
    for (int i = 0; i < 8; ++i)
#pragma unroll
        for (int j = 0; j < 8; ++j) acc[i][j] = 0.f;

    int cur = cls[0];
    float4* xsf4 = (float4*)xs;

    for (int stage = 0; stage < CHUNK / STAGE; ++stage) {
        int sb = stage * STAGE;
        if (sb >= rows) break;  // uniform across block
        // stage rows sb..sb+STAGE into LDS (gather via perm)
#pragma unroll
        for (int it = 0; it < (STAGE * P / 4) / NTHR; ++it) {  // 8 iters
            int f4 = it * NTHR + tid;
            int rl = f4 >> 5;       // P/4 = 32 float4 per row
            int c4 = f4 & 31;
            int rg = sb + rl;
            if (rg < rows)
                xsf4[f4] = ((const float4*)(x + (size_t)pm[rg] * P))[c4];
        }
        __syncthreads();

        int nr = min(STAGE, rows - sb);
        for (int rl = 0; rl < nr; ++rl) {
            int c = cls[sb + rl];           // uniform across block
            if (c != cur) {                 // class-run boundary: flush
#pragma unroll
                for (int i = 0; i < 8; ++i)
#pragma unroll
                    for (int j = 0; j < 8; ++j) {
                        atomicAdd(&grams[(size_t)cur * P * P + (ti * 8 + i) * P + tj * 8 + j],
                                  acc[i][j]);
                        acc[i][j] = 0.f;
                    }
                cur = c;
            }
            float4 va0 = xsf4[rl * 32 + ti * 2];
            float4 va1 = xsf4[rl * 32 + ti * 2 + 1];
            float4 vb0 = xsf4[rl * 32 + tj * 2];
            float4 vb1 = xsf4[rl * 32 + tj * 2 + 1];
            float a[8] = {va0.x, va0.y, va0.z, va0.w, va1.x, va1.y, va1.z, va1.w};
            float b[8] = {vb0.x, vb0.y, vb0.z, vb0.w, vb1.x, vb1.y, vb1.z, vb1.w};
#pragma unroll
            for (int i = 0; i < 8; ++i)
#pragma unroll
                for (int j = 0; j < 8; ++j) acc[i][j] = fmaf(a[i], b[j], acc[i][j]);
        }
        __syncthreads();
    }
    // final flush
#pragma unroll
    for (int i = 0; i < 8; ++i)
#pragma unroll
        for (int j = 0; j < 8; ++j)
            atomicAdd(&grams[(size_t)cur * P * P + (ti * 8 + i) * P + tj * 8 + j], acc[i][j]);
}

// ---------------- logdet(I + s*G) via LU (no pivoting; diag-dominant SPD) ----
// block 0: s = GAM1*p/(m*eps) over sum of class grams (discrimn_empi)
// block 1: s =      p/(m*eps) over sum of class grams (discrimn_theo)
// block 2+c: s = p/(max(cnt,1)*eps) over grams[c]
__global__ __launch_bounds__(NTHR) void logdet_kernel(const float* __restrict__ grams,
                                                      const int* __restrict__ counts,
                                                      float* __restrict__ logd, int m) {
    __shared__ float A[P * P];   // 64 KB, unpadded: trailing update is column-parallel
    int tid = threadIdx.x;
    int b = blockIdx.x;
    float scale;
    if (b == 0) scale = GAM1 * (float)P / ((float)m * EPSV);
    else if (b == 1) scale = (float)P / ((float)m * EPSV);
    else {
        float cnt = (float)counts[b - 2];
        if (cnt < 1.f) cnt = 1.f;
        scale = (float)P / (cnt * EPSV);
    }
    if (b < 2) {
        for (int idx = tid; idx < P * P; idx += NTHR) {
            float s = 0.f;
            for (int c = 0; c < K; ++c) s += grams[c * P * P + idx];
            int r = idx >> 7, cc = idx & (P - 1);
            A[idx] = scale * s + (r == cc ? 1.f : 0.f);
        }
    } else {
        const float* g = grams + (size_t)(b - 2) * P * P;
        for (int idx = tid; idx < P * P; idx += NTHR) {
            int r = idx >> 7, cc = idx & (P - 1);
            A[idx] = scale * g[idx] + (r == cc ? 1.f : 0.f);
        }
    }
    __syncthreads();

    for (int j = 0; j < P - 1; ++j) {
        float inv = 1.0f / A[j * P + j];
        // normalize column j (L factors)
        for (int i = j + 1 + tid; i < P; i += NTHR) A[i * P + j] *= inv;
        __syncthreads();
        // trailing update: thread owns column k, loops rows (bank-conflict-free)
        int k = j + 1 + tid;
        if (k < P) {
            float ajk = A[j * P + k];
            for (int i = j + 1; i < P; ++i)
                A[i * P + k] -= A[i * P + j] * ajk;   // A[i*P+j] broadcasts
        }
        __syncthreads();
    }
    // logdet = sum log(U_jj); logd[b] pre-zeroed by memset
    if (tid < P) atomicAdd(&logd[b], logf(A[tid * P + tid]));
}

// ---------------- combine into the 4 outputs ----------------
__global__ void final_kernel(const float* __restrict__ logd, const int* __restrict__ counts,
                             float* __restrict__ out, int m) {
    if (threadIdx.x == 0 && blockIdx.x == 0) {
        float empi = 0.5f * logd[0];
        float theo = 0.5f * logd[1];
        float comp = 0.f;
        for (int c = 0; c < K; ++c) {
            float cnt = (float)counts[c];
            if (cnt > 0.f) comp += logd[2 + c] * cnt / (float)m;
        }
        comp *= 0.5f;
        out[0] = GAM2 * (-empi) + comp;
        out[1] = empi;
        out[2] = theo;
        out[3] = comp;
    }
}

extern "C" void kernel_launch(void* const* d_in, const int* in_sizes, int n_in,
                              void* d_out, int out_size, void* d_ws, size_t ws_size,
                              hipStream_t stream) {
    const float* x = (const float*)d_in[0];
    const int* y = (const int*)d_in[1];
    int m = in_sizes[1];
    int nb = (m + CHUNK - 1) / CHUNK;

    // workspace layout (bytes)
    char* ws = (char*)d_ws;
    float* grams = (float*)ws;                              // K*P*P*4 = 655360
    float* logd = (float*)(ws + 655360);                    // (K+2) floats, pad to 64
    int* counts = (int*)(ws + 655424);                      // K ints, pad to 64
    int* blk_counts = (int*)(ws + 655488);                  // nb*K ints
    int* blk_offsets = (int*)(ws + 655488 + (size_t)nb * K * 4);
    int* perm = (int*)(ws + 655488 + 2 * (size_t)nb * K * 4);

    // zero grams + logd (+counts, harmlessly): atomics accumulate into these
    hipMemsetAsync(ws, 0, 655488, stream);

    hist_kernel<<<nb, NTHR, 0, stream>>>(y, blk_counts, m);
    scan_kernel<<<1, NTHR, 0, stream>>>(blk_counts, blk_offsets, counts, nb);
    scatter_kernel<<<nb, NTHR, 0, stream>>>(y, blk_offsets, perm, m);
    gram_kernel<<<nb, NTHR, 0, stream>>>(x, y, perm, grams, m);
    logdet_kernel<<<K + 2, NTHR, 0, stream>>>(grams, counts, logd, m);
    final_kernel<<<1, 1, 0, stream>>>(logd, counts, (float*)d_out, m);
}

// Round 2
// 350.408 us; speedup vs baseline: 2.7444x; 2.7444x over previous
//
#include <hip/hip_runtime.h>

// MCR^2 loss, m x p fp32 x, labels y in [0,K). m=262144, p=128, K=10.
#define K 10
#define P 128
#define EPSV 0.01f
#define GAM1 1.0f
#define GAM2 1.0f
#define CH 512      // rows per gram block (class segments padded to multiple of CH)
#define SK 64       // staged rows (k-depth) per LDS stage
#define KS 68       // LDS k-stride in bf16 elems (64 + 4 pad, keeps b64s 2-way-free)
#define SORTCH 2048 // rows per sort block
#define NTHR 256

typedef __attribute__((ext_vector_type(8))) short bf16x8;
typedef __attribute__((ext_vector_type(4))) short s16x4;
typedef __attribute__((ext_vector_type(4))) float f32x4;

static __device__ __forceinline__ short f2bf(float f) {
    unsigned u = __float_as_uint(f);
    u = (u + 0x7FFFu + ((u >> 16) & 1u)) >> 16;   // RNE
    return (short)u;
}

// ---------------- histogram per sort-block ----------------
__global__ void hist_kernel(const int* __restrict__ y, int* __restrict__ blk_counts, int m) {
    __shared__ int h[K];
    int t = threadIdx.x;
    if (t < K) h[t] = 0;
    __syncthreads();
    int base = blockIdx.x * SORTCH;
    int rows = min(SORTCH, m - base);
    for (int i = t; i < rows; i += NTHR) atomicAdd(&h[y[base + i]], 1);
    __syncthreads();
    if (t < K) blk_counts[blockIdx.x * K + t] = h[t];
}

// ---------------- parallel scan of block counts; padded class starts ----------
__global__ void scan_kernel(const int* __restrict__ blk_counts, int* __restrict__ blk_offsets,
                            int* __restrict__ counts, int* __restrict__ pstart, int nb) {
    __shared__ int s[K][128];
    __shared__ int sps[K + 1];
    int t = threadIdx.x;
    int own[K];
    if (t < 128) {
        for (int c = 0; c < K; ++c) {
            int v = (t < nb) ? blk_counts[t * K + c] : 0;
            own[c] = v;
            s[c][t] = v;
        }
    }
    __syncthreads();
    for (int off = 1; off < 128; off <<= 1) {
        int tmp[K];
        if (t < 128)
            for (int c = 0; c < K; ++c) tmp[c] = (t >= off) ? s[c][t - off] : 0;
        __syncthreads();
        if (t < 128)
            for (int c = 0; c < K; ++c) s[c][t] += tmp[c];
        __syncthreads();
    }
    if (t == 0) {
        int run = 0;
        for (int c = 0; c < K; ++c) {
            sps[c] = run;
            int tot = s[c][127];
            counts[c] = tot;
            pstart[c] = run;
            run += ((tot + CH - 1) / CH) * CH;   // pad each class to multiple of CH
        }
        sps[K] = run;
        pstart[K] = run;
    }
    __syncthreads();
    if (t < nb)
        for (int c = 0; c < K; ++c)
            blk_offsets[t * K + c] = sps[c] + s[c][t] - own[c];   // exclusive + padded base
}

// ---------------- scatter row indices into padded class-sorted perm -----------
__global__ void scatter_kernel(const int* __restrict__ y, const int* __restrict__ blk_offsets,
                               int* __restrict__ perm, int m) {
    __shared__ int cur[K];
    int t = threadIdx.x;
    if (t < K) cur[t] = blk_offsets[blockIdx.x * K + t];
    __syncthreads();
    int base = blockIdx.x * SORTCH;
    int rows = min(SORTCH, m - base);
    for (int i = t; i < rows; i += NTHR) {
        int row = base + i;
        int pos = atomicAdd(&cur[y[row]], 1);
        perm[pos] = row;
    }
}

// ---------------- per-class Gram via bf16 MFMA --------------------------------
// Block = CH sorted rows of ONE class (padding rows perm=-1 -> zeros).
// LDS tile is k-transposed bf16: xsT[col][k], stride KS, so MFMA fragments are
// 8 contiguous bf16 per lane (A[m=lane&15][k=quad*8+j], verified layout).
__global__ __launch_bounds__(NTHR) void gram_kernel(const float* __restrict__ x,
                                                    const int* __restrict__ perm,
                                                    const int* __restrict__ pstart,
                                                    float* __restrict__ grams) {
    __shared__ int pm[CH];
    __shared__ short xsT[P * KS];   // 17408 B
    int t = threadIdx.x;
    long base = (long)blockIdx.x * CH;
    int cls = 0;
    for (int c = 1; c < K; ++c)
        if (base >= (long)pstart[c]) cls = c;
    for (int i = t; i < CH; i += NTHR) pm[i] = perm[base + i];

    const int lane = t & 63;
    const int wave = t >> 6;
    const int m16 = lane & 15;
    const int quad = lane >> 4;
    const int wr = wave >> 1;   // tile-row half (gram rows wr*64..+64)
    const int wc = wave & 1;    // tile-col half
    const int c2 = t & 63;      // staging: float2 column pair (cols 2*c2, 2*c2+1)
    const int rg = t >> 6;      // staging: row group of 16

    f32x4 acc[4][4];
#pragma unroll
    for (int a = 0; a < 4; ++a)
#pragma unroll
        for (int b = 0; b < 4; ++b) acc[a][b] = (f32x4){0.f, 0.f, 0.f, 0.f};

    __syncthreads();   // pm visible

    for (int s = 0; s < CH / SK; ++s) {
        int sb = s * SK;
        // gather SK rows (coalesced: one wave instr = 512B of one row)
        float2 v[16];
#pragma unroll
        for (int ii = 0; ii < 16; ++ii) {
            int r = pm[sb + rg * 16 + ii];
            if (r >= 0) v[ii] = ((const float2*)(x + (size_t)r * P))[c2];
            else { v[ii].x = 0.f; v[ii].y = 0.f; }
        }
        __syncthreads();   // prior stage fully consumed
        short b0[16], b1[16];
#pragma unroll
        for (int ii = 0; ii < 16; ++ii) { b0[ii] = f2bf(v[ii].x); b1[ii] = f2bf(v[ii].y); }
        int col0 = 2 * c2, col1 = 2 * c2 + 1;
#pragma unroll
        for (int q = 0; q < 4; ++q) {
            s16x4 w0 = {b0[q * 4], b0[q * 4 + 1], b0[q * 4 + 2], b0[q * 4 + 3]};
            s16x4 w1 = {b1[q * 4], b1[q * 4 + 1], b1[q * 4 + 2], b1[q * 4 + 3]};
            *(s16x4*)&xsT[col0 * KS + rg * 16 + q * 4] = w0;
            *(s16x4*)&xsT[col1 * KS + rg * 16 + q * 4] = w1;
        }
        __syncthreads();
        // 2 k-steps of 32
#pragma unroll
        for (int kk = 0; kk < 2; ++kk) {
            int k0 = kk * 32 + quad * 8;
            bf16x8 af[4], bfr[4];
#pragma unroll
            for (int a = 0; a < 4; ++a) {
                int colA = wr * 64 + a * 16 + m16;
                union { bf16x8 v8; s16x4 h[2]; } u;
                u.h[0] = *(s16x4*)&xsT[colA * KS + k0];
                u.h[1] = *(s16x4*)&xsT[colA * KS + k0 + 4];
                af[a] = u.v8;
            }
#pragma unroll
            for (int b = 0; b < 4; ++b) {
                int colB = wc * 64 + b * 16 + m16;
                union { bf16x8 v8; s16x4 h[2]; } u;
                u.h[0] = *(s16x4*)&xsT[colB * KS + k0];
                u.h[1] = *(s16x4*)&xsT[colB * KS + k0 + 4];
                bfr[b] = u.v8;
            }
#pragma unroll
            for (int a = 0; a < 4; ++a)
#pragma unroll
                for (int b = 0; b < 4; ++b)
                    acc[a][b] = __builtin_amdgcn_mfma_f32_16x16x32_bf16(af[a], bfr[b], acc[a][b], 0, 0, 0);
        }
    }
    // flush upper triangle only (Gram symmetric)
    float* g = grams + (size_t)cls * P * P;
#pragma unroll
    for (int a = 0; a < 4; ++a)
#pragma unroll
        for (int b = 0; b < 4; ++b)
#pragma unroll
            for (int r = 0; r < 4; ++r) {
                int gi = wr * 64 + a * 16 + quad * 4 + r;
                int gj = wc * 64 + b * 16 + m16;
                if (gi <= gj) atomicAdd(&g[gi * P + gj], acc[a][b][r]);
            }
}

// ---------------- logdet(I + s*G), LU no pivot, 1024 threads, float4-wide -----
__global__ __launch_bounds__(1024) void logdet_kernel(const float* __restrict__ grams,
                                                      const int* __restrict__ counts,
                                                      float* __restrict__ logd, int m) {
    __shared__ float A[P * P];   // 64 KB
    int t = threadIdx.x, b = blockIdx.x;
    float scale;
    if (b == 0) scale = GAM1 * (float)P / ((float)m * EPSV);
    else if (b == 1) scale = (float)P / ((float)m * EPSV);
    else {
        float cnt = (float)counts[b - 2];
        if (cnt < 1.f) cnt = 1.f;
        scale = (float)P / (cnt * EPSV);
    }
    for (int idx = t; idx < P * P; idx += 1024) {
        int i = idx >> 7, c = idx & (P - 1);
        int src = (i <= c) ? (i * P + c) : (c * P + i);   // grams hold upper triangle
        float sgm;
        if (b < 2) {
            float ssum = 0.f;
            for (int cc = 0; cc < K; ++cc) ssum += grams[cc * P * P + src];
            sgm = ssum;
        } else {
            sgm = grams[(b - 2) * P * P + src];
        }
        A[idx] = scale * sgm + ((i == c) ? 1.f : 0.f);
    }
    __syncthreads();

    const int cq = t & 31;     // column quad: cols 4*cq..+3
    const int rg = t >> 5;     // 0..31 row group
    const int c0 = cq * 4;
    for (int j = 0; j < P - 1; ++j) {
        float inv = 1.0f / A[j * P + j];
        if (c0 + 3 > j) {
            f32x4 ajc = *(f32x4*)&A[j * P + c0];
            if (c0 + 0 <= j) ajc[0] = 0.f;   // cols <= j: identity rewrite (same-value)
            if (c0 + 1 <= j) ajc[1] = 0.f;
            if (c0 + 2 <= j) ajc[2] = 0.f;
            for (int i = j + 1 + rg; i < P; i += 32) {
                float lij = A[i * P + j] * inv;
                f32x4 vv = *(f32x4*)&A[i * P + c0];
                vv[0] -= lij * ajc[0];
                vv[1] -= lij * ajc[1];
                vv[2] -= lij * ajc[2];
                vv[3] -= lij * ajc[3];
                *(f32x4*)&A[i * P + c0] = vv;
            }
        }
        __syncthreads();
    }
    if (t < P) atomicAdd(&logd[b], logf(A[t * P + t]));
}

// ---------------- combine ----------------
__global__ void final_kernel(const float* __restrict__ logd, const int* __restrict__ counts,
                             float* __restrict__ out, int m) {
    if (threadIdx.x == 0 && blockIdx.x == 0) {
        float empi = 0.5f * logd[0];
        float theo = 0.5f * logd[1];
        float comp = 0.f;
        for (int c = 0; c < K; ++c) {
            float cnt = (float)counts[c];
            if (cnt > 0.f) comp += logd[2 + c] * cnt / (float)m;
        }
        comp *= 0.5f;
        out[0] = GAM2 * (-empi) + comp;
        out[1] = empi;
        out[2] = theo;
        out[3] = comp;
    }
}

extern "C" void kernel_launch(void* const* d_in, const int* in_sizes, int n_in,
                              void* d_out, int out_size, void* d_ws, size_t ws_size,
                              hipStream_t stream) {
    const float* x = (const float*)d_in[0];
    const int* y = (const int*)d_in[1];
    int m = in_sizes[1];
    int nbs = (m + SORTCH - 1) / SORTCH;   // 128 sort blocks
    int nbg = (m + CH - 1) / CH + K;       // 522 gram blocks (covers worst-case padding)

    char* ws = (char*)d_ws;
    float* grams = (float*)ws;                               // K*P*P*4 = 655360
    float* logd = (float*)(ws + 655360);                     // 12 floats
    int* counts = (int*)(ws + 655424);                       // 10 ints
    int* pstart = (int*)(ws + 655488);                       // 11 ints
    int* blk_counts = (int*)(ws + 655616);                   // nbs*K
    int* blk_offsets = (int*)(ws + 655616 + (size_t)nbs * K * 4);
    int* perm = (int*)(ws + 655616 + 2 * (size_t)nbs * K * 4);   // nbg*CH ints

    hipMemsetAsync(ws, 0, 655488, stream);                       // grams + logd
    hipMemsetAsync(perm, 0xFF, (size_t)nbg * CH * 4, stream);    // perm = -1

    hist_kernel<<<nbs, NTHR, 0, stream>>>(y, blk_counts, m);
    scan_kernel<<<1, NTHR, 0, stream>>>(blk_counts, blk_offsets, counts, pstart, nbs);
    scatter_kernel<<<nbs, NTHR, 0, stream>>>(y, blk_offsets, perm, m);
    gram_kernel<<<nbg, NTHR, 0, stream>>>(x, perm, pstart, grams);
    logdet_kernel<<<K + 2, 1024, 0, stream>>>(grams, counts, logd, m);
    final_kernel<<<1, 1, 0, stream>>>(logd, counts, (float*)d_out, m);
}